// Round 12
// baseline (206.047 us; speedup 1.0000x reference)
//
#include <hip/hip_runtime.h>
#include <hip/hip_bf16.h>
#include <stdint.h>

typedef __attribute__((ext_vector_type(4))) int i32x4;     // i8 MFMA A/B/C: 4 dwords

#define K_TOT 4096
#define N_TOT 4096

// ---------------- fused prepass: x-quant (blocks < nqb) + w-pack (rest) -------------
__global__ __launch_bounds__(512) void prep_kernel(const float4* __restrict__ x4,
                                                   unsigned int* __restrict__ xq_dw,
                                                   float* __restrict__ s_row,
                                                   int* __restrict__ qsum_row,
                                                   const int4* __restrict__ wq,
                                                   unsigned int* __restrict__ w8,
                                                   int nqb) {
    const int wave = threadIdx.x >> 6, lane = threadIdx.x & 63;
    if ((int)blockIdx.x < nqb) {
        const long row = (long)blockIdx.x * 8 + wave;
        const float4* xr = x4 + row * (K_TOT / 4);
        float4 v[16];
        float amax = 0.f;
#pragma unroll
        for (int i = 0; i < 16; ++i) {
            v[i] = xr[lane + i * 64];
            amax = fmaxf(amax, fmaxf(fmaxf(fabsf(v[i].x), fabsf(v[i].y)),
                                     fmaxf(fabsf(v[i].z), fabsf(v[i].w))));
        }
#pragma unroll
        for (int off = 32; off; off >>= 1) amax = fmaxf(amax, __shfl_xor(amax, off));
        amax = fmaxf(amax, 1e-30f);
        const float inv = 127.0f / amax;
        int qsum = 0;
        unsigned int* out = xq_dw + row * (K_TOT / 4);
#pragma unroll
        for (int i = 0; i < 16; ++i) {
            int q0 = (int)rintf(v[i].x * inv), q1 = (int)rintf(v[i].y * inv);
            int q2 = (int)rintf(v[i].z * inv), q3 = (int)rintf(v[i].w * inv);
            qsum += q0 + q1 + q2 + q3;
            out[lane + i * 64] = (unsigned int)(q0 & 255) | ((unsigned int)(q1 & 255) << 8) |
                                 ((unsigned int)(q2 & 255) << 16) | ((unsigned int)(q3 & 255) << 24);
        }
#pragma unroll
        for (int off = 32; off; off >>= 1) qsum += __shfl_xor(qsum, off);
        if (lane == 0) { s_row[row] = amax / 127.0f; qsum_row[row] = qsum; }
    } else {
        const long o = (long)((int)blockIdx.x - nqb) * 8 + wave;
        const int4* src = wq + o * (K_TOT / 4);
        unsigned int* dst = w8 + o * (K_TOT / 4);
#pragma unroll
        for (int i = 0; i < 16; ++i) {
            int4 q = src[lane + i * 64];
            dst[lane + i * 64] =
                (unsigned int)((q.x - 128) & 255) | ((unsigned int)((q.y - 128) & 255) << 8) |
                ((unsigned int)((q.z - 128) & 255) << 16) | ((unsigned int)((q.w - 128) & 255) << 24);
        }
    }
}

// ================= 128x256 i8 GEMM, 64x64 wave tiles, 4 waves/SIMD ==================
// D[M,N](i32) = Xq[M,K](i8) * W8[N,K](i8)^T via mfma_i32_16x16x64_i8.
// 8 waves (2M x 4N) of 64x64 -> acc 64 VGPR; total <=128/wave (launch_bounds(512,4))
// -> 16 waves/CU = TWO independent co-resident blocks: cross-block wave skew puts
// read-phase and MFMA-phase waves on each SIMD simultaneously (the overlap all
// barrier-locked 2-wave/SIMD variants [R3/R4/R6/R8/R10] could not get).
// LDS: 3 x 24KB (A 8K + B 16K) = 72 KB/block (144/CU). 1 phase per K-tile:
//   Phase t: 8 ds_reads frags(t)<-buf[t%3] | 3-load stage(t+2)->buf[(t+2)%3]
//            | 16 MFMA | vmcnt(3) (retires stage(t+1), keeps stage(t+2)) | BAR
// WAR: buf[(t+2)%3] last read in phase t-1; a wave passes BAR(t-1) only after its
// MFMAs issued, which required its ds_reads complete (lgkm) -> overwrite safe.
// Read-before-write: frags(t+1) read after all waves' vmcnt(3)+BAR ✓.
// Swizzle: LDS dest linear (global_load_lds), 16B-chunk XOR ((row>>1)&3) on global
// source and identically on ds_read -> <=2-way conflicts (free).

#define BAR() __builtin_amdgcn_s_barrier()
#define VMCNT3() asm volatile("s_waitcnt vmcnt(3)" ::: "memory")
#define VMCNT0() asm volatile("s_waitcnt vmcnt(0)" ::: "memory")
#define PRIO1() __builtin_amdgcn_s_setprio(1)
#define PRIO0() __builtin_amdgcn_s_setprio(0)

__launch_bounds__(512, 4)
__global__ void gemm64_i8_kernel(const char* __restrict__ Aq,   // [M][K] i8
                                 const char* __restrict__ Bq,   // [N][K] i8
                                 const float* __restrict__ s_row,
                                 const int* __restrict__ qsum_row,
                                 const float* __restrict__ scale,
                                 const int* __restrict__ zp,
                                 const float* __restrict__ bias,
                                 float* __restrict__ C) {
    __shared__ __align__(16) char lds[3][24576];      // [buf][A:0..8191 | B:8192..24575]

    const int nbn = N_TOT / 256;                      // 16
    int bid = blockIdx.x;
    const int nwg = gridDim.x;
    if ((nwg & 7) == 0) {                             // T1: bijective XCD swizzle
        const int cpx = nwg >> 3;
        bid = (bid & 7) * cpx + (bid >> 3);
    }
    const int bm = bid / nbn, bn = bid % nbn;

    const int tid = threadIdx.x;
    const int w = tid >> 6, lane = tid & 63;
    const int wr = w >> 2, wc = w & 3;                // 2x4 wave grid, 64x64 each
    const int fr = lane & 15, kg = lane >> 4;         // fragment row / k-group
    const int sw = (fr >> 1) & 3;                     // read-side chunk swizzle

    const long a_row0 = (long)bm * 128;
    const long b_row0 = (long)bn * 256;

    i32x4 acc[4][4] = {};
    i32x4 a[4], b[4];

    // stage one K-tile (A 128x64=8KB: 1 load/thread; B 256x64=16KB: 2 loads/thread)
    auto stage = [&](int t, char* buf) {
        {   // A
            const int row = w * 16 + (lane >> 2);
            const int c = (lane & 3) ^ ((row >> 1) & 3);
            const char* g = Aq + (a_row0 + row) * (long)K_TOT + (long)t * 64 + c * 16;
            __builtin_amdgcn_global_load_lds(
                (const __attribute__((address_space(1))) void*)g,
                (__attribute__((address_space(3))) void*)(buf + w * 1024), 16, 0, 0);
        }
#pragma unroll
        for (int r = 0; r < 2; ++r) {                 // B
            const int j = w * 2 + r;                  // 16 chunks of 16 rows
            const int row = j * 16 + (lane >> 2);
            const int c = (lane & 3) ^ ((row >> 1) & 3);
            const char* g = Bq + (b_row0 + row) * (long)K_TOT + (long)t * 64 + c * 16;
            __builtin_amdgcn_global_load_lds(
                (const __attribute__((address_space(1))) void*)g,
                (__attribute__((address_space(3))) void*)(buf + 8192 + j * 1024), 16, 0, 0);
        }
    };

    auto read_frags = [&](const char* buf) {
        const char* Ab = buf;
        const char* Bb = buf + 8192;
#pragma unroll
        for (int mi = 0; mi < 4; ++mi)
            a[mi] = *(const i32x4*)(Ab + (wr * 64 + mi * 16 + fr) * 64 + ((kg ^ sw) << 4));
#pragma unroll
        for (int ni = 0; ni < 4; ++ni)
            b[ni] = *(const i32x4*)(Bb + (wc * 64 + ni * 16 + fr) * 64 + ((kg ^ sw) << 4));
    };

    auto mfma16 = [&]() {
        PRIO1();
#pragma unroll
        for (int mi = 0; mi < 4; ++mi)
#pragma unroll
            for (int ni = 0; ni < 4; ++ni)
                acc[mi][ni] = __builtin_amdgcn_mfma_i32_16x16x64_i8(a[mi], b[ni], acc[mi][ni], 0, 0, 0);
        PRIO0();
    };

    // prologue: stage tiles 0,1; retire 0 (keep 1 in flight); BAR.
    stage(0, lds[0]);
    stage(1, lds[1]);
    VMCNT3();
    BAR();

    // phases t = 0..59 (always stage t+2, vmcnt(3))
#pragma unroll 1
    for (int it = 0; it < 20; ++it) {
        const int t = it * 3;
        read_frags(lds[0]); stage(t + 2, lds[2]); mfma16(); VMCNT3(); BAR();
        read_frags(lds[1]); stage(t + 3, lds[0]); mfma16(); VMCNT3(); BAR();
        read_frags(lds[2]); stage(t + 4, lds[1]); mfma16(); VMCNT3(); BAR();
    }
    // t=60: stage 62; t=61: stage 63; t=62: drain; t=63: last
    read_frags(lds[0]); stage(62, lds[2]); mfma16(); VMCNT3(); BAR();
    read_frags(lds[1]); stage(63, lds[0]); mfma16(); VMCNT3(); BAR();
    read_frags(lds[2]); mfma16(); VMCNT0(); BAR();
    read_frags(lds[0]); mfma16();

    // epilogue: y = (scale[col]*s[row]) * (acc + (128-zp[col])*qsum[row]) + bias[col]
    float scs[4], c1s[4], bbs[4]; int cols[4];
#pragma unroll
    for (int n = 0; n < 4; ++n) {
        cols[n] = (int)b_row0 + wc * 64 + n * 16 + fr;
        scs[n] = scale[cols[n]];
        c1s[n] = (float)(128 - zp[cols[n]]);
        bbs[n] = bias[cols[n]];
    }
#pragma unroll
    for (int m = 0; m < 4; ++m) {
#pragma unroll
        for (int j = 0; j < 4; ++j) {
            const long r = a_row0 + wr * 64 + m * 16 + kg * 4 + j;
            const float sr = s_row[r];
            const float qs = (float)qsum_row[r];
#pragma unroll
            for (int n = 0; n < 4; ++n)
                C[r * N_TOT + cols[n]] = ((float)acc[m][n][j] + c1s[n] * qs) * (scs[n] * sr) + bbs[n];
        }
    }
}

// ---------------- fallback (ws too small / M%128!=0): fp32 tiled GEMM ----------------
__global__ void fallback_kernel(const float* __restrict__ x, const int* __restrict__ wq,
                                const int* __restrict__ zp, const float* __restrict__ sc,
                                const float* __restrict__ bs, float* __restrict__ y) {
    __shared__ float xs[32][33];
    __shared__ float ws[32][33];
    int bm = blockIdx.y, bn = blockIdx.x;
    int tid = threadIdx.x;
    int r = tid >> 5, c = tid & 31;
    float acc[4] = {0.f, 0.f, 0.f, 0.f};
    for (int k0 = 0; k0 < K_TOT; k0 += 32) {
        for (int t = tid; t < 32 * 32; t += 256) {
            int rr = t >> 5, cc = t & 31;
            xs[rr][cc] = x[(long)(bm * 32 + rr) * K_TOT + k0 + cc];
            int o = bn * 32 + rr;
            ws[rr][cc] = (float)(wq[(long)o * K_TOT + k0 + cc] - zp[o]);
        }
        __syncthreads();
#pragma unroll
        for (int kk = 0; kk < 32; ++kk) {
            float wv = ws[c][kk];
#pragma unroll
            for (int j = 0; j < 4; ++j) acc[j] += xs[r + 8 * j][kk] * wv;
        }
        __syncthreads();
    }
    int o = bn * 32 + c;
    float s = sc[o], b = bs[o];
#pragma unroll
    for (int j = 0; j < 4; ++j)
        y[(long)(bm * 32 + r + 8 * j) * N_TOT + o] = acc[j] * s + b;
}

extern "C" void kernel_launch(void* const* d_in, const int* in_sizes, int n_in,
                              void* d_out, int out_size, void* d_ws, size_t ws_size,
                              hipStream_t stream) {
    const float* x = (const float*)d_in[0];
    const int* wq = (const int*)d_in[1];
    const int* zp = (const int*)d_in[2];
    const float* sc = (const float*)d_in[3];
    const float* bs = (const float*)d_in[4];
    float* y = (float*)d_out;

    const long M = (long)in_sizes[0] / K_TOT;   // 8192

    size_t xq_bytes = (size_t)M * K_TOT;              // 33.5 MB
    size_t w8_bytes = (size_t)N_TOT * K_TOT;          // 16.8 MB
    size_t s_bytes = (size_t)M * 4;
    size_t q_bytes = (size_t)M * 4;
    size_t need = xq_bytes + w8_bytes + s_bytes + q_bytes + 256;

    if (ws_size >= need && (M & 127) == 0) {
        char* p = (char*)d_ws;
        char* xq = p;                       p += xq_bytes;
        char* w8 = p;                       p += w8_bytes;
        float* s_row = (float*)p;           p += s_bytes;
        int* qsum_row = (int*)p;

        const int nqb = (int)(M / 8);                       // 1024 quant blocks
        const int npb = N_TOT / 8;                          // 512 pack blocks
        prep_kernel<<<nqb + npb, 512, 0, stream>>>(
            (const float4*)x, (unsigned int*)xq, s_row, qsum_row,
            (const int4*)wq, (unsigned int*)w8, nqb);

        dim3 grid((unsigned)((M / 128) * (N_TOT / 256)));   // 1024
        gemm64_i8_kernel<<<grid, 512, 0, stream>>>(
            xq, w8, s_row, qsum_row, sc, zp, bs, y);
    } else {
        dim3 grid(N_TOT / 32, (unsigned)(M / 32));
        fallback_kernel<<<grid, 256, 0, stream>>>(x, wq, zp, sc, bs, y);
    }
}